// Round 2
// baseline (23622.920 us; speedup 1.0000x reference)
//
#include <hip/hip_runtime.h>

#define NN 81920
#define NE 180224
#define NB 2048
#define D 300
#define NL 5
#define CH 8192           // GEMM row-chunk (keeps the [*,600] intermediate small)

static constexpr float TEMP_INV = 25.0f;   // 1/0.04
static constexpr float BN_EPS_C = 1e-5f;

// ---------------- init h = atom_emb1[x0] + atom_emb2[x1] ----------------
__global__ void k_init_h(const int* __restrict__ x, const float* __restrict__ ae1,
                         const float* __restrict__ ae2, float* __restrict__ h) {
  int i = blockIdx.x;
  int i0 = x[2 * i], i1 = x[2 * i + 1];
  const float* r1 = ae1 + (size_t)i0 * D;
  const float* r2 = ae2 + (size_t)i1 * D;
  float* ho = h + (size_t)i * D;
  for (int f = threadIdx.x; f < D; f += blockDim.x) ho[f] = r1[f] + r2[f];
}

// ---------------- CSR build ----------------
__global__ void k_count(const int* __restrict__ ei, int* __restrict__ cnt) {
  int e = blockIdx.x * blockDim.x + threadIdx.x;
  if (e < NE) atomicAdd(&cnt[ei[NE + e]], 1);
}

__global__ void k_scan(const int* __restrict__ cnt, int* __restrict__ rs) {
  __shared__ int sdata[1024];
  int t = threadIdx.x;
  int base = t * 80;                 // 1024*80 == 81920 exactly
  int s = 0;
  for (int j = 0; j < 80; ++j) s += cnt[base + j];
  sdata[t] = s;
  __syncthreads();
  for (int off = 1; off < 1024; off <<= 1) {
    int v = (t >= off) ? sdata[t - off] : 0;
    __syncthreads();
    sdata[t] += v;
    __syncthreads();
  }
  int run = sdata[t] - s;            // exclusive prefix
  for (int j = 0; j < 80; ++j) { rs[base + j] = run; run += cnt[base + j]; }
  if (t == 1023) rs[NN] = run;
}

__global__ void k_bucket(const int* __restrict__ ei, const int* __restrict__ ea,
                         const int* __restrict__ rs, int* __restrict__ fill,
                         int* __restrict__ srcs, int* __restrict__ attrs) {
  int e = blockIdx.x * blockDim.x + threadIdx.x;
  if (e >= NE) return;
  int d = ei[NE + e];
  int p = rs[d] + atomicAdd(&fill[d], 1);
  srcs[p] = ei[e];
  attrs[p] = ea[2 * e] | (ea[2 * e + 1] << 8);
}

// ---------------- per-layer edge aggregation (gather form) ----------------
// agg[i] = h[i] + T1[4] + T2[0] + sum_{e: dst=i} (h[src_e] + T1[a0_e] + T2[a1_e])
__global__ void k_gather(const float* __restrict__ h, const int* __restrict__ rs,
                         const int* __restrict__ srcs, const int* __restrict__ attrs,
                         const float* __restrict__ T1, const float* __restrict__ T2,
                         float* __restrict__ agg) {
  int i = blockIdx.x;
  int j0 = rs[i], j1 = rs[i + 1];
  int f0 = threadIdx.x;              // blockDim = 128
  int f1 = f0 + 128;
  int f2 = f0 + 256;
  const float* hi = h + (size_t)i * D;
  float a0 = hi[f0] + T1[4 * D + f0] + T2[f0];
  float a1 = hi[f1] + T1[4 * D + f1] + T2[f1];
  float a2 = (f2 < D) ? (hi[f2] + T1[4 * D + f2] + T2[f2]) : 0.f;
  for (int j = j0; j < j1; ++j) {
    int s = srcs[j];
    int at = attrs[j];
    const float* hs = h + (size_t)s * D;
    const float* t1 = T1 + (size_t)(at & 255) * D;
    const float* t2 = T2 + (size_t)(at >> 8) * D;
    a0 += hs[f0] + t1[f0] + t2[f0];
    a1 += hs[f1] + t1[f1] + t2[f1];
    if (f2 < D) a2 += hs[f2] + t1[f2] + t2[f2];
  }
  float* ao = agg + (size_t)i * D;
  ao[f0] = a0;
  ao[f1] = a1;
  if (f2 < D) ao[f2] = a2;
}

// ---------------- fp32 tiled GEMM: C[M,Nc] = op(A[M,K] @ B[K,Nc] + bias) ----------------
template <bool RELU, bool BIAS>
__global__ __launch_bounds__(256) void k_gemm(const float* __restrict__ A,
                                              const float* __restrict__ Bm,
                                              const float* __restrict__ bias,
                                              float* __restrict__ C,
                                              int M, int K, int Nc) {
  __shared__ float As[8][132];
  __shared__ float Bs[8][132];
  int tid = threadIdx.x;
  int tx = tid & 15, ty = tid >> 4;
  int m0 = blockIdx.x * 128, n0 = blockIdx.y * 128;
  float acc[8][8] = {};
  int ar = tid >> 1, akq = (tid & 1) * 4;   // A tile: 128 rows x 8 k
  int bk = tid >> 5, bn = (tid & 31) * 4;   // B tile: 8 k x 128 n
  for (int kk = 0; kk < K; kk += 8) {
    {
      int gr = m0 + ar;
      int gk = kk + akq;
      if (gr < M && gk + 3 < K) {
        float4 v = *(const float4*)(A + (size_t)gr * K + gk);
        As[akq + 0][ar] = v.x; As[akq + 1][ar] = v.y;
        As[akq + 2][ar] = v.z; As[akq + 3][ar] = v.w;
      } else {
#pragma unroll
        for (int u = 0; u < 4; ++u)
          As[akq + u][ar] = (gr < M && gk + u < K) ? A[(size_t)gr * K + gk + u] : 0.f;
      }
    }
    {
      int gk = kk + bk;
      int gn = n0 + bn;
      if (gk < K && gn + 3 < Nc) {
        *(float4*)&Bs[bk][bn] = *(const float4*)(Bm + (size_t)gk * Nc + gn);
      } else {
#pragma unroll
        for (int u = 0; u < 4; ++u)
          Bs[bk][bn + u] = (gk < K && gn + u < Nc) ? Bm[(size_t)gk * Nc + gn + u] : 0.f;
      }
    }
    __syncthreads();
#pragma unroll
    for (int k = 0; k < 8; ++k) {
      float4 a0 = *(const float4*)&As[k][ty * 8];
      float4 a1 = *(const float4*)&As[k][ty * 8 + 4];
      float4 b0 = *(const float4*)&Bs[k][tx * 8];
      float4 b1 = *(const float4*)&Bs[k][tx * 8 + 4];
      float av[8] = {a0.x, a0.y, a0.z, a0.w, a1.x, a1.y, a1.z, a1.w};
      float bv[8] = {b0.x, b0.y, b0.z, b0.w, b1.x, b1.y, b1.z, b1.w};
#pragma unroll
      for (int i = 0; i < 8; ++i)
#pragma unroll
        for (int j = 0; j < 8; ++j) acc[i][j] = fmaf(av[i], bv[j], acc[i][j]);
    }
    __syncthreads();
  }
  int rbase = m0 + ty * 8, cbase = n0 + tx * 8;
#pragma unroll
  for (int i = 0; i < 8; ++i) {
    int r = rbase + i;
    if (r >= M) break;
#pragma unroll
    for (int j = 0; j < 8; ++j) {
      int c = cbase + j;
      if (c >= Nc) continue;
      float v = acc[i][j];
      if (BIAS) v += bias[c];
      if (RELU) v = fmaxf(v, 0.f);
      C[(size_t)r * Nc + c] = v;
    }
  }
}

// ---------------- BN ----------------
__global__ void k_bnstats(const float* __restrict__ X, float* __restrict__ stats) {
  int t = threadIdx.x;               // 256
  int r0 = blockIdx.x * 256;
  float s0 = 0, q0 = 0, s1 = 0, q1 = 0;
  int c1 = t + 256;
  for (int r = r0; r < r0 + 256; ++r) {
    const float* row = X + (size_t)r * D;
    float v = row[t];
    s0 += v; q0 += v * v;
    if (c1 < D) { float w = row[c1]; s1 += w; q1 += w * w; }
  }
  atomicAdd(&stats[t], s0);
  atomicAdd(&stats[D + t], q0);
  if (c1 < D) { atomicAdd(&stats[c1], s1); atomicAdd(&stats[D + c1], q1); }
}

__global__ void k_bnfinal(const float* __restrict__ stats, const float* __restrict__ g,
                          const float* __restrict__ b, float* __restrict__ scsh) {
  int t = threadIdx.x;
  if (t >= D) return;
  float mean = stats[t] * (1.0f / NN);
  float var = stats[D + t] * (1.0f / NN) - mean * mean;
  float inv = rsqrtf(var + BN_EPS_C);
  float sc = g[t] * inv;
  scsh[t] = sc;
  scsh[D + t] = b[t] - mean * sc;
}

template <bool RELU>
__global__ void k_bnapply(float* __restrict__ X, const float* __restrict__ scsh) {
  int i = blockIdx.x;
  float* row = X + (size_t)i * D;
  for (int f = threadIdx.x; f < D; f += blockDim.x) {
    float v = fmaf(row[f], scsh[f], scsh[D + f]);
    if (RELU) v = fmaxf(v, 0.f);
    row[f] = v;
  }
}

// ---------------- pooling (batch is sorted) ----------------
__global__ void k_gstart(const int* __restrict__ batch, int* __restrict__ gs) {
  int i = blockIdx.x * blockDim.x + threadIdx.x;
  if (i >= NN) return;
  int b = batch[i];
  int bp = (i == 0) ? -1 : batch[i - 1];
  for (int q = bp + 1; q <= b; ++q) gs[q] = i;
  if (i == NN - 1)
    for (int q = b + 1; q <= NB; ++q) gs[q] = NN;
}

__global__ void k_poolseg(const float* __restrict__ h, const int* __restrict__ gs,
                          float* __restrict__ g) {
  int b = blockIdx.x;
  int j0 = gs[b], j1 = gs[b + 1];
  int t = threadIdx.x;               // 128
  float s0 = 0, s1 = 0, s2 = 0;
  int c2 = t + 256;
  for (int j = j0; j < j1; ++j) {
    const float* row = h + (size_t)j * D;
    s0 += row[t];
    s1 += row[t + 128];
    if (c2 < D) s2 += row[c2];
  }
  float invc = 1.f / (float)((j1 - j0) > 1 ? (j1 - j0) : 1);
  float* go = g + (size_t)b * D;
  go[t] = s0 * invc;
  go[t + 128] = s1 * invc;
  if (c2 < D) go[c2] = s2 * invc;
}

// ---------------- row L2 normalize ----------------
__global__ void k_norm(const float* __restrict__ pin, float* __restrict__ feat, int ro) {
  int b = blockIdx.x;
  int t = threadIdx.x;               // 64 = one wave
  const float* row = pin + (size_t)b * D;
  float q = 0;
  for (int c = t; c < D; c += 64) { float v = row[c]; q += v * v; }
#pragma unroll
  for (int off = 32; off > 0; off >>= 1) q += __shfl_down(q, off);
  q = __shfl(q, 0);
  float inv = 1.f / fmaxf(sqrtf(q), 1e-12f);
  float* fo = feat + (size_t)(ro + b) * D;
  for (int c = t; c < D; c += 64) fo[c] = row[c] * inv;
}

// ---------------- sim = F F^T fused with NT-Xent logits layout ----------------
__global__ __launch_bounds__(256) void k_logits(const float* __restrict__ F,
                                                float* __restrict__ out) {
  __shared__ float As[8][132];
  __shared__ float Bs[8][132];
  int tid = threadIdx.x;
  int tx = tid & 15, ty = tid >> 4;
  int m0 = blockIdx.x * 128, n0 = blockIdx.y * 128;
  float acc[8][8] = {};
  int lr = tid >> 1, lkq = (tid & 1) * 4;
  for (int kk = 0; kk < D; kk += 8) {
    int gk = kk + lkq;
    const float* arow = F + (size_t)(m0 + lr) * D;
    const float* brow = F + (size_t)(n0 + lr) * D;
    if (gk + 3 < D) {
      float4 va = *(const float4*)(arow + gk);
      As[lkq + 0][lr] = va.x; As[lkq + 1][lr] = va.y;
      As[lkq + 2][lr] = va.z; As[lkq + 3][lr] = va.w;
      float4 vb = *(const float4*)(brow + gk);
      Bs[lkq + 0][lr] = vb.x; Bs[lkq + 1][lr] = vb.y;
      Bs[lkq + 2][lr] = vb.z; Bs[lkq + 3][lr] = vb.w;
    } else {
#pragma unroll
      for (int u = 0; u < 4; ++u) {
        As[lkq + u][lr] = (gk + u < D) ? arow[gk + u] : 0.f;
        Bs[lkq + u][lr] = (gk + u < D) ? brow[gk + u] : 0.f;
      }
    }
    __syncthreads();
#pragma unroll
    for (int k = 0; k < 8; ++k) {
      float4 a0 = *(const float4*)&As[k][ty * 8];
      float4 a1 = *(const float4*)&As[k][ty * 8 + 4];
      float4 b0 = *(const float4*)&Bs[k][tx * 8];
      float4 b1 = *(const float4*)&Bs[k][tx * 8 + 4];
      float av[8] = {a0.x, a0.y, a0.z, a0.w, a1.x, a1.y, a1.z, a1.w};
      float bv[8] = {b0.x, b0.y, b0.z, b0.w, b1.x, b1.y, b1.z, b1.w};
#pragma unroll
      for (int i = 0; i < 8; ++i)
#pragma unroll
        for (int j = 0; j < 8; ++j) acc[i][j] = fmaf(av[i], bv[j], acc[i][j]);
    }
    __syncthreads();
  }
  int rbase = m0 + ty * 8, cbase = n0 + tx * 8;
#pragma unroll
  for (int i = 0; i < 8; ++i) {
    int r = rbase + i;
    int posj = (r + NB) & 4095;
#pragma unroll
    for (int j = 0; j < 8; ++j) {
      int c = cbase + j;
      if (c == r) continue;
      float v = acc[i][j] * TEMP_INV;
      int slot = (c == posj) ? 0 : (1 + c - (c > r) - (c > posj));
      out[(size_t)r * 4095 + slot] = v;
    }
  }
}

// ---------------- host ----------------
extern "C" void kernel_launch(void* const* d_in, const int* in_sizes, int n_in,
                              void* d_out, int out_size, void* d_ws, size_t ws_size,
                              hipStream_t stream) {
  const int* xs[2] = {(const int*)d_in[0], (const int*)d_in[4]};
  const int* eis[2] = {(const int*)d_in[1], (const int*)d_in[5]};
  const int* eas[2] = {(const int*)d_in[2], (const int*)d_in[6]};
  const int* bts[2] = {(const int*)d_in[3], (const int*)d_in[7]};
  const float* ae1 = (const float*)d_in[8];
  const float* ae2 = (const float*)d_in[9];
  const float* ee1 = (const float*)d_in[10];   // [5,6,300]
  const float* ee2 = (const float*)d_in[11];   // [5,3,300]
  const float* W1 = (const float*)d_in[12];    // [5,300,600]
  const float* b1 = (const float*)d_in[13];    // [5,600]
  const float* W2 = (const float*)d_in[14];    // [5,600,300]
  const float* b2 = (const float*)d_in[15];    // [5,300]
  const float* bng = (const float*)d_in[16];
  const float* bnb = (const float*)d_in[17];
  const float* pW1 = (const float*)d_in[18];
  const float* pb1 = (const float*)d_in[19];
  const float* pW2 = (const float*)d_in[20];
  const float* pb2 = (const float*)d_in[21];

  char* p = (char*)d_ws;
  auto alloc = [&](size_t bytes) -> void* {
    void* q = (void*)p;
    p += (bytes + 255) & ~(size_t)255;
    return q;
  };
  float* h    = (float*)alloc((size_t)NN * D * 4);     //  98.3 MB
  float* agg  = (float*)alloc((size_t)NN * D * 4);     //  98.3 MB
  float* slab = (float*)alloc((size_t)CH * 600 * 4);   //  19.7 MB (chunked GEMM1 out)
  int* cnt    = (int*)alloc((size_t)NN * 4);
  int* rs     = (int*)alloc((size_t)(NN + 1) * 4);
  int* srcs   = (int*)alloc((size_t)NE * 4);
  int* attrs  = (int*)alloc((size_t)NE * 4);
  float* stats = (float*)alloc(600 * 4);
  float* scsh  = (float*)alloc(600 * 4);
  int* gstart  = (int*)alloc((size_t)(NB + 1) * 4);
  float* pg   = (float*)alloc((size_t)NB * D * 4);
  float* pt   = (float*)alloc((size_t)NB * D * 4);
  float* feat = (float*)alloc((size_t)2 * NB * D * 4);
  // total ≈ 228 MB

  for (int v = 0; v < 2; ++v) {
    k_init_h<<<NN, 128, 0, stream>>>(xs[v], ae1, ae2, h);
    hipMemsetAsync(cnt, 0, (size_t)NN * 4, stream);
    k_count<<<(NE + 255) / 256, 256, 0, stream>>>(eis[v], cnt);
    k_scan<<<1, 1024, 0, stream>>>(cnt, rs);
    hipMemsetAsync(cnt, 0, (size_t)NN * 4, stream);
    k_bucket<<<(NE + 255) / 256, 256, 0, stream>>>(eis[v], eas[v], rs, cnt, srcs, attrs);

    for (int l = 0; l < NL; ++l) {
      k_gather<<<NN, 128, 0, stream>>>(h, rs, srcs, attrs, ee1 + (size_t)l * 6 * D,
                                       ee2 + (size_t)l * 3 * D, agg);
      for (int c0 = 0; c0 < NN; c0 += CH) {
        k_gemm<true, true><<<dim3(CH / 128, (600 + 127) / 128), 256, 0, stream>>>(
            agg + (size_t)c0 * D, W1 + (size_t)l * D * 600, b1 + (size_t)l * 600,
            slab, CH, D, 600);
        k_gemm<false, true><<<dim3(CH / 128, (D + 127) / 128), 256, 0, stream>>>(
            slab, W2 + (size_t)l * 600 * D, b2 + (size_t)l * D,
            h + (size_t)c0 * D, CH, 600, D);
      }
      hipMemsetAsync(stats, 0, 600 * 4, stream);
      k_bnstats<<<NN / 256, 256, 0, stream>>>(h, stats);
      k_bnfinal<<<1, 320, 0, stream>>>(stats, bng + (size_t)l * D, bnb + (size_t)l * D, scsh);
      if (l < NL - 1)
        k_bnapply<true><<<NN, 128, 0, stream>>>(h, scsh);
      else
        k_bnapply<false><<<NN, 128, 0, stream>>>(h, scsh);
    }

    k_gstart<<<(NN + 255) / 256, 256, 0, stream>>>(bts[v], gstart);
    k_poolseg<<<NB, 128, 0, stream>>>(h, gstart, pg);
    k_gemm<true, true><<<dim3(NB / 128, (D + 127) / 128), 256, 0, stream>>>(
        pg, pW1, pb1, pt, NB, D, D);
    k_gemm<false, true><<<dim3(NB / 128, (D + 127) / 128), 256, 0, stream>>>(
        pt, pW2, pb2, pg, NB, D, D);
    k_norm<<<NB, 64, 0, stream>>>(pg, feat, v * NB);
  }

  k_logits<<<dim3(32, 32), 256, 0, stream>>>(feat, (float*)d_out);
  hipMemsetAsync((float*)d_out + (size_t)4096 * 4095, 0, (size_t)4096 * 4, stream);
}

// Round 4
// 12829.695 us; speedup vs baseline: 1.8413x; 1.8413x over previous
//
#include <hip/hip_runtime.h>

#define NN 81920
#define NE 180224
#define NB 2048
#define D 300
#define NL 5
#define CH 8192
#define KP1 320          // padded K for GEMM1 (agg planes stride)
#define NP1 640          // padded N for GEMM1 (slab stride)
#define KP2 640          // padded K for GEMM2 (= NP1)
#define NP2 320          // padded N for GEMM2
#define FKP 320          // feature planes stride (logits K)

static constexpr float TEMP_INV = 25.0f;   // 1/0.04
static constexpr float BN_EPS_C = 1e-5f;

typedef __attribute__((ext_vector_type(8))) short short8;
typedef __attribute__((ext_vector_type(4))) float f32x4;

__device__ inline void split_bf16(float v, short& hi, short& lo) {
  unsigned u = __float_as_uint(v);
  hi = (short)(u >> 16);
  float r = v - __uint_as_float(u & 0xffff0000u);
  lo = (short)(__float_as_uint(r) >> 16);
}

// ---------------- init h = atom_emb1[x0] + atom_emb2[x1] ----------------
__global__ void k_init_h(const int* __restrict__ x, const float* __restrict__ ae1,
                         const float* __restrict__ ae2, float* __restrict__ h) {
  int i = blockIdx.x;
  int i0 = x[2 * i], i1 = x[2 * i + 1];
  const float* r1 = ae1 + (size_t)i0 * D;
  const float* r2 = ae2 + (size_t)i1 * D;
  float* ho = h + (size_t)i * D;
  for (int f = threadIdx.x; f < D; f += blockDim.x) ho[f] = r1[f] + r2[f];
}

// ---------------- CSR build ----------------
__global__ void k_count(const int* __restrict__ ei, int* __restrict__ cnt) {
  int e = blockIdx.x * blockDim.x + threadIdx.x;
  if (e < NE) atomicAdd(&cnt[ei[NE + e]], 1);
}

__global__ void k_scan(const int* __restrict__ cnt, int* __restrict__ rs) {
  __shared__ int sdata[1024];
  int t = threadIdx.x;
  int base = t * 80;                 // 1024*80 == 81920
  int s = 0;
  for (int j = 0; j < 80; ++j) s += cnt[base + j];
  sdata[t] = s;
  __syncthreads();
  for (int off = 1; off < 1024; off <<= 1) {
    int v = (t >= off) ? sdata[t - off] : 0;
    __syncthreads();
    sdata[t] += v;
    __syncthreads();
  }
  int run = sdata[t] - s;
  for (int j = 0; j < 80; ++j) { rs[base + j] = run; run += cnt[base + j]; }
  if (t == 1023) rs[NN] = run;
}

__global__ void k_bucket(const int* __restrict__ ei, const int* __restrict__ ea,
                         const int* __restrict__ rs, int* __restrict__ fill,
                         int* __restrict__ srcs, int* __restrict__ attrs) {
  int e = blockIdx.x * blockDim.x + threadIdx.x;
  if (e >= NE) return;
  int d = ei[NE + e];
  int p = rs[d] + atomicAdd(&fill[d], 1);
  srcs[p] = ei[e];
  attrs[p] = ea[2 * e] | (ea[2 * e + 1] << 8);
}

// ---------------- gather: agg = h+selfloop+sum(h[src]+e), written as bf16 hi/lo planes --
__global__ void k_gather(const float* __restrict__ h, const int* __restrict__ rs,
                         const int* __restrict__ srcs, const int* __restrict__ attrs,
                         const float* __restrict__ T1, const float* __restrict__ T2,
                         short* __restrict__ aggH, short* __restrict__ aggL) {
  int i = blockIdx.x;
  int j0 = rs[i], j1 = rs[i + 1];
  int t = threadIdx.x;               // 128
  int f0 = t, f1 = t + 128, f2 = t + 256;   // f2 in [256,384)
  const float* hi = h + (size_t)i * D;
  float a0 = hi[f0] + T1[4 * D + f0] + T2[f0];
  float a1 = hi[f1] + T1[4 * D + f1] + T2[f1];
  float a2 = (f2 < D) ? (hi[f2] + T1[4 * D + f2] + T2[f2]) : 0.f;
  for (int j = j0; j < j1; ++j) {
    int s = srcs[j];
    int at = attrs[j];
    const float* hs = h + (size_t)s * D;
    const float* t1 = T1 + (size_t)(at & 255) * D;
    const float* t2 = T2 + (size_t)(at >> 8) * D;
    a0 += hs[f0] + t1[f0] + t2[f0];
    a1 += hs[f1] + t1[f1] + t2[f1];
    if (f2 < D) a2 += hs[f2] + t1[f2] + t2[f2];
  }
  size_t base = (size_t)i * KP1;
  short hh, ll;
  split_bf16(a0, hh, ll); aggH[base + f0] = hh; aggL[base + f0] = ll;
  split_bf16(a1, hh, ll); aggH[base + f1] = hh; aggL[base + f1] = ll;
  if (f2 < KP1) {            // covers pad cols 300..319 with exact zeros
    split_bf16(a2, hh, ll); aggH[base + f2] = hh; aggL[base + f2] = ll;
  }
}

// ---------------- weight pre-transpose + split:  T[n][k] = W[k][n], zero-padded --------
__global__ void k_prepw(const float* __restrict__ W, short* __restrict__ TH,
                        short* __restrict__ TL, int K, int Nc, int Kp, int Np) {
  int idx = blockIdx.x * blockDim.x + threadIdx.x;
  int per = Np * Kp;
  if (idx >= NL * per) return;
  int l = idx / per, r = idx % per;
  int n = r / Kp, k = r % Kp;
  float v = (n < Nc && k < K) ? W[(size_t)l * K * Nc + (size_t)k * Nc + n] : 0.f;
  short hi, lo;
  split_bf16(v, hi, lo);
  TH[idx] = hi;
  TL[idx] = lo;
}

// ---------------- split-bf16 MFMA GEMM, tile 128x64, 4 waves, no LDS ----------------
// C = A[M,KK] @ B^T-planes[N,KK]  (3-term split product, fp32 accumulate)
// MODE 0: relu(bias+C) -> split -> CHp/CLp planes (stride ldcp), all cols written
// MODE 1: bias+C -> fp32 Cf (stride ldcf), cols < maskN only
template <int MODE, int KK>
__global__ __launch_bounds__(256) void k_mfma_gemm(
    const short* __restrict__ AH, const short* __restrict__ AL,
    const short* __restrict__ BH, const short* __restrict__ BL,
    const float* __restrict__ bias, int biasN,
    short* __restrict__ CHp, short* __restrict__ CLp, int ldcp,
    float* __restrict__ Cf, int ldcf, int maskN) {
  int lane = threadIdx.x & 63;
  int w = threadIdx.x >> 6;
  int m0 = blockIdx.x * 128 + (w >> 1) * 64;
  int n0 = blockIdx.y * 64 + (w & 1) * 32;
  int rl = lane & 15;
  int kg = (lane >> 4) * 8;
  f32x4 acc[4][2] = {};
  for (int k0 = 0; k0 < KK; k0 += 32) {
    int kk = k0 + kg;
    short8 aH[4], aL[4], bH[2], bL[2];
#pragma unroll
    for (int rf = 0; rf < 4; ++rf) {
      size_t off = (size_t)(m0 + rf * 16 + rl) * KK + kk;
      aH[rf] = *(const short8*)(AH + off);
      aL[rf] = *(const short8*)(AL + off);
    }
#pragma unroll
    for (int cf = 0; cf < 2; ++cf) {
      size_t off = (size_t)(n0 + cf * 16 + rl) * KK + kk;
      bH[cf] = *(const short8*)(BH + off);
      bL[cf] = *(const short8*)(BL + off);
    }
#pragma unroll
    for (int rf = 0; rf < 4; ++rf)
#pragma unroll
      for (int cf = 0; cf < 2; ++cf) {
        acc[rf][cf] = __builtin_amdgcn_mfma_f32_16x16x32_bf16(aH[rf], bH[cf], acc[rf][cf], 0, 0, 0);
        acc[rf][cf] = __builtin_amdgcn_mfma_f32_16x16x32_bf16(aH[rf], bL[cf], acc[rf][cf], 0, 0, 0);
        acc[rf][cf] = __builtin_amdgcn_mfma_f32_16x16x32_bf16(aL[rf], bH[cf], acc[rf][cf], 0, 0, 0);
      }
  }
#pragma unroll
  for (int rf = 0; rf < 4; ++rf) {
#pragma unroll
    for (int cf = 0; cf < 2; ++cf) {
      int col = n0 + cf * 16 + rl;
      float bv = (col < biasN) ? bias[col] : 0.f;
#pragma unroll
      for (int i = 0; i < 4; ++i) {
        int row = m0 + rf * 16 + (lane >> 4) * 4 + i;
        float v = acc[rf][cf][i] + bv;
        if (MODE == 0) {
          v = fmaxf(v, 0.f);
          short hi, lo;
          split_bf16(v, hi, lo);
          CHp[(size_t)row * ldcp + col] = hi;
          CLp[(size_t)row * ldcp + col] = lo;
        } else {
          if (col < maskN) Cf[(size_t)row * ldcf + col] = v;
        }
      }
    }
  }
}

// ---------------- fp32 tiled GEMM (projector only) ----------------
template <bool RELU>
__global__ __launch_bounds__(256) void k_gemm(const float* __restrict__ A,
                                              const float* __restrict__ Bm,
                                              const float* __restrict__ bias,
                                              float* __restrict__ C,
                                              int M, int K, int Nc) {
  __shared__ float As[8][132];
  __shared__ float Bs[8][132];
  int tid = threadIdx.x;
  int tx = tid & 15, ty = tid >> 4;
  int m0 = blockIdx.x * 128, n0 = blockIdx.y * 128;
  float acc[8][8] = {};
  int ar = tid >> 1, akq = (tid & 1) * 4;
  int bk = tid >> 5, bn = (tid & 31) * 4;
  for (int kk = 0; kk < K; kk += 8) {
    {
      int gr = m0 + ar, gk = kk + akq;
      if (gr < M && gk + 3 < K) {
        float4 v = *(const float4*)(A + (size_t)gr * K + gk);
        As[akq + 0][ar] = v.x; As[akq + 1][ar] = v.y;
        As[akq + 2][ar] = v.z; As[akq + 3][ar] = v.w;
      } else {
#pragma unroll
        for (int u = 0; u < 4; ++u)
          As[akq + u][ar] = (gr < M && gk + u < K) ? A[(size_t)gr * K + gk + u] : 0.f;
      }
    }
    {
      int gk = kk + bk, gn = n0 + bn;
      if (gk < K && gn + 3 < Nc) {
        *(float4*)&Bs[bk][bn] = *(const float4*)(Bm + (size_t)gk * Nc + gn);
      } else {
#pragma unroll
        for (int u = 0; u < 4; ++u)
          Bs[bk][bn + u] = (gk < K && gn + u < Nc) ? Bm[(size_t)gk * Nc + gn + u] : 0.f;
      }
    }
    __syncthreads();
#pragma unroll
    for (int k = 0; k < 8; ++k) {
      float4 a0 = *(const float4*)&As[k][ty * 8];
      float4 a1 = *(const float4*)&As[k][ty * 8 + 4];
      float4 b0 = *(const float4*)&Bs[k][tx * 8];
      float4 b1 = *(const float4*)&Bs[k][tx * 8 + 4];
      float av[8] = {a0.x, a0.y, a0.z, a0.w, a1.x, a1.y, a1.z, a1.w};
      float bv[8] = {b0.x, b0.y, b0.z, b0.w, b1.x, b1.y, b1.z, b1.w};
#pragma unroll
      for (int i = 0; i < 8; ++i)
#pragma unroll
        for (int j = 0; j < 8; ++j) acc[i][j] = fmaf(av[i], bv[j], acc[i][j]);
    }
    __syncthreads();
  }
  int rbase = m0 + ty * 8, cbase = n0 + tx * 8;
#pragma unroll
  for (int i = 0; i < 8; ++i) {
    int r = rbase + i;
    if (r >= M) break;
#pragma unroll
    for (int j = 0; j < 8; ++j) {
      int c = cbase + j;
      if (c >= Nc) continue;
      float v = acc[i][j] + bias[c];
      if (RELU) v = fmaxf(v, 0.f);
      C[(size_t)r * Nc + c] = v;
    }
  }
}

// ---------------- BN ----------------
__global__ void k_bnstats(const float* __restrict__ X, float* __restrict__ stats) {
  int t = threadIdx.x;               // 256
  int r0 = blockIdx.x * 256;
  float s0 = 0, q0 = 0, s1 = 0, q1 = 0;
  int c1 = t + 256;
  for (int r = r0; r < r0 + 256; ++r) {
    const float* row = X + (size_t)r * D;
    float v = row[t];
    s0 += v; q0 += v * v;
    if (c1 < D) { float w = row[c1]; s1 += w; q1 += w * w; }
  }
  atomicAdd(&stats[t], s0);
  atomicAdd(&stats[D + t], q0);
  if (c1 < D) { atomicAdd(&stats[c1], s1); atomicAdd(&stats[D + c1], q1); }
}

__global__ void k_bnfinal(const float* __restrict__ stats, const float* __restrict__ g,
                          const float* __restrict__ b, float* __restrict__ scsh) {
  int t = threadIdx.x;
  if (t >= D) return;
  float mean = stats[t] * (1.0f / NN);
  float var = stats[D + t] * (1.0f / NN) - mean * mean;
  float inv = rsqrtf(var + BN_EPS_C);
  float sc = g[t] * inv;
  scsh[t] = sc;
  scsh[D + t] = b[t] - mean * sc;
}

template <bool RELU>
__global__ void k_bnapply(float* __restrict__ X, const float* __restrict__ scsh) {
  int i = blockIdx.x;
  float* row = X + (size_t)i * D;
  for (int f = threadIdx.x; f < D; f += blockDim.x) {
    float v = fmaf(row[f], scsh[f], scsh[D + f]);
    if (RELU) v = fmaxf(v, 0.f);
    row[f] = v;
  }
}

// ---------------- pooling (batch sorted) ----------------
__global__ void k_gstart(const int* __restrict__ batch, int* __restrict__ gs) {
  int i = blockIdx.x * blockDim.x + threadIdx.x;
  if (i >= NN) return;
  int b = batch[i];
  int bp = (i == 0) ? -1 : batch[i - 1];
  for (int q = bp + 1; q <= b; ++q) gs[q] = i;
  if (i == NN - 1)
    for (int q = b + 1; q <= NB; ++q) gs[q] = NN;
}

__global__ void k_poolseg(const float* __restrict__ h, const int* __restrict__ gs,
                          float* __restrict__ g) {
  int b = blockIdx.x;
  int j0 = gs[b], j1 = gs[b + 1];
  int t = threadIdx.x;               // 128
  float s0 = 0, s1 = 0, s2 = 0;
  int c2 = t + 256;
  for (int j = j0; j < j1; ++j) {
    const float* row = h + (size_t)j * D;
    s0 += row[t];
    s1 += row[t + 128];
    if (c2 < D) s2 += row[c2];
  }
  float invc = 1.f / (float)((j1 - j0) > 1 ? (j1 - j0) : 1);
  float* go = g + (size_t)b * D;
  go[t] = s0 * invc;
  go[t + 128] = s1 * invc;
  if (c2 < D) go[c2] = s2 * invc;
}

// ---------------- L2 normalize -> split feature planes [4096, FKP] ----------------
__global__ void k_norm(const float* __restrict__ pin, short* __restrict__ FH,
                       short* __restrict__ FL, int ro) {
  int b = blockIdx.x;
  int t = threadIdx.x;               // 64
  const float* row = pin + (size_t)b * D;
  float q = 0;
  for (int c = t; c < D; c += 64) { float v = row[c]; q += v * v; }
#pragma unroll
  for (int off = 32; off > 0; off >>= 1) q += __shfl_down(q, off);
  q = __shfl(q, 0);
  float inv = 1.f / fmaxf(sqrtf(q), 1e-12f);
  size_t base = (size_t)(ro + b) * FKP;
  for (int c = t; c < FKP; c += 64) {
    float v = (c < D) ? row[c] * inv : 0.f;
    short hi, lo;
    split_bf16(v, hi, lo);
    FH[base + c] = hi;
    FL[base + c] = lo;
  }
}

// ---------------- MFMA sim = F F^T fused with NT-Xent logits layout ----------------
__global__ __launch_bounds__(256) void k_logits_mfma(const short* __restrict__ FH,
                                                     const short* __restrict__ FL,
                                                     float* __restrict__ out) {
  int lane = threadIdx.x & 63;
  int w = threadIdx.x >> 6;
  int m0 = blockIdx.x * 128 + (w >> 1) * 64;
  int n0 = blockIdx.y * 64 + (w & 1) * 32;
  int rl = lane & 15;
  int kg = (lane >> 4) * 8;
  f32x4 acc[4][2] = {};
  for (int k0 = 0; k0 < FKP; k0 += 32) {
    int kk = k0 + kg;
    short8 aH[4], aL[4], bH[2], bL[2];
#pragma unroll
    for (int rf = 0; rf < 4; ++rf) {
      size_t off = (size_t)(m0 + rf * 16 + rl) * FKP + kk;
      aH[rf] = *(const short8*)(FH + off);
      aL[rf] = *(const short8*)(FL + off);
    }
#pragma unroll
    for (int cf = 0; cf < 2; ++cf) {
      size_t off = (size_t)(n0 + cf * 16 + rl) * FKP + kk;
      bH[cf] = *(const short8*)(FH + off);
      bL[cf] = *(const short8*)(FL + off);
    }
#pragma unroll
    for (int rf = 0; rf < 4; ++rf)
#pragma unroll
      for (int cf = 0; cf < 2; ++cf) {
        acc[rf][cf] = __builtin_amdgcn_mfma_f32_16x16x32_bf16(aH[rf], bH[cf], acc[rf][cf], 0, 0, 0);
        acc[rf][cf] = __builtin_amdgcn_mfma_f32_16x16x32_bf16(aH[rf], bL[cf], acc[rf][cf], 0, 0, 0);
        acc[rf][cf] = __builtin_amdgcn_mfma_f32_16x16x32_bf16(aL[rf], bH[cf], acc[rf][cf], 0, 0, 0);
      }
  }
#pragma unroll
  for (int rf = 0; rf < 4; ++rf) {
#pragma unroll
    for (int cf = 0; cf < 2; ++cf) {
      int c = n0 + cf * 16 + rl;
#pragma unroll
      for (int i = 0; i < 4; ++i) {
        int r = m0 + rf * 16 + (lane >> 4) * 4 + i;
        if (c == r) continue;
        float v = acc[rf][cf][i] * TEMP_INV;
        int posj = (r + NB) & 4095;
        int slot = (c == posj) ? 0 : (1 + c - (c > r) - (c > posj));
        out[(size_t)r * 4095 + slot] = v;
      }
    }
  }
}

// ---------------- host ----------------
extern "C" void kernel_launch(void* const* d_in, const int* in_sizes, int n_in,
                              void* d_out, int out_size, void* d_ws, size_t ws_size,
                              hipStream_t stream) {
  const int* xs[2] = {(const int*)d_in[0], (const int*)d_in[4]};
  const int* eis[2] = {(const int*)d_in[1], (const int*)d_in[5]};
  const int* eas[2] = {(const int*)d_in[2], (const int*)d_in[6]};
  const int* bts[2] = {(const int*)d_in[3], (const int*)d_in[7]};
  const float* ae1 = (const float*)d_in[8];
  const float* ae2 = (const float*)d_in[9];
  const float* ee1 = (const float*)d_in[10];
  const float* ee2 = (const float*)d_in[11];
  const float* W1 = (const float*)d_in[12];
  const float* b1 = (const float*)d_in[13];
  const float* W2 = (const float*)d_in[14];
  const float* b2 = (const float*)d_in[15];
  const float* bng = (const float*)d_in[16];
  const float* bnb = (const float*)d_in[17];
  const float* pW1 = (const float*)d_in[18];
  const float* pb1 = (const float*)d_in[19];
  const float* pW2 = (const float*)d_in[20];
  const float* pb2 = (const float*)d_in[21];

  char* p = (char*)d_ws;
  auto alloc = [&](size_t bytes) -> void* {
    void* q = (void*)p;
    p += (bytes + 255) & ~(size_t)255;
    return q;
  };
  float* h    = (float*)alloc((size_t)NN * D * 4);          // 98.3 MB
  short* aggH = (short*)alloc((size_t)NN * KP1 * 2);        // 52.4 MB
  short* aggL = (short*)alloc((size_t)NN * KP1 * 2);        // 52.4 MB
  short* slabH = (short*)alloc((size_t)CH * NP1 * 2);       // 10.5 MB
  short* slabL = (short*)alloc((size_t)CH * NP1 * 2);       // 10.5 MB
  short* w1tH = (short*)alloc((size_t)NL * NP1 * KP1 * 2);  // 2.05 MB
  short* w1tL = (short*)alloc((size_t)NL * NP1 * KP1 * 2);
  short* w2tH = (short*)alloc((size_t)NL * NP2 * KP2 * 2);  // 2.05 MB
  short* w2tL = (short*)alloc((size_t)NL * NP2 * KP2 * 2);
  short* featH = (short*)alloc((size_t)2 * NB * FKP * 2);   // 2.6 MB
  short* featL = (short*)alloc((size_t)2 * NB * FKP * 2);
  int* cnt    = (int*)alloc((size_t)NN * 4);
  int* rs     = (int*)alloc((size_t)(NN + 1) * 4);
  int* srcs   = (int*)alloc((size_t)NE * 4);
  int* attrs  = (int*)alloc((size_t)NE * 4);
  float* stats = (float*)alloc(600 * 4);
  float* scsh  = (float*)alloc(600 * 4);
  int* gstart  = (int*)alloc((size_t)(NB + 1) * 4);
  float* pg   = (float*)alloc((size_t)NB * D * 4);
  float* pt   = (float*)alloc((size_t)NB * D * 4);
  // total ~ 245 MB

  // weight transpose+split (all layers)
  k_prepw<<<(NL * NP1 * KP1 + 255) / 256, 256, 0, stream>>>(W1, w1tH, w1tL, 300, 600, KP1, NP1);
  k_prepw<<<(NL * NP2 * KP2 + 255) / 256, 256, 0, stream>>>(W2, w2tH, w2tL, 600, 300, KP2, NP2);

  for (int v = 0; v < 2; ++v) {
    k_init_h<<<NN, 128, 0, stream>>>(xs[v], ae1, ae2, h);
    hipMemsetAsync(cnt, 0, (size_t)NN * 4, stream);
    k_count<<<(NE + 255) / 256, 256, 0, stream>>>(eis[v], cnt);
    k_scan<<<1, 1024, 0, stream>>>(cnt, rs);
    hipMemsetAsync(cnt, 0, (size_t)NN * 4, stream);
    k_bucket<<<(NE + 255) / 256, 256, 0, stream>>>(eis[v], eas[v], rs, cnt, srcs, attrs);

    for (int l = 0; l < NL; ++l) {
      k_gather<<<NN, 128, 0, stream>>>(h, rs, srcs, attrs, ee1 + (size_t)l * 6 * D,
                                       ee2 + (size_t)l * 3 * D, aggH, aggL);
      for (int c0 = 0; c0 < NN; c0 += CH) {
        k_mfma_gemm<0, KP1><<<dim3(CH / 128, NP1 / 64), 256, 0, stream>>>(
            aggH + (size_t)c0 * KP1, aggL + (size_t)c0 * KP1,
            w1tH + (size_t)l * NP1 * KP1, w1tL + (size_t)l * NP1 * KP1,
            b1 + (size_t)l * 600, 600, slabH, slabL, NP1, nullptr, 0, 0);
        k_mfma_gemm<1, KP2><<<dim3(CH / 128, NP2 / 64), 256, 0, stream>>>(
            slabH, slabL,
            w2tH + (size_t)l * NP2 * KP2, w2tL + (size_t)l * NP2 * KP2,
            b2 + (size_t)l * 300, 300, nullptr, nullptr, 0,
            h + (size_t)c0 * D, D, 300);
      }
      hipMemsetAsync(stats, 0, 600 * 4, stream);
      k_bnstats<<<NN / 256, 256, 0, stream>>>(h, stats);
      k_bnfinal<<<1, 320, 0, stream>>>(stats, bng + (size_t)l * D, bnb + (size_t)l * D, scsh);
      if (l < NL - 1)
        k_bnapply<true><<<NN, 128, 0, stream>>>(h, scsh);
      else
        k_bnapply<false><<<NN, 128, 0, stream>>>(h, scsh);
    }

    k_gstart<<<(NN + 255) / 256, 256, 0, stream>>>(bts[v], gstart);
    k_poolseg<<<NB, 128, 0, stream>>>(h, gstart, pg);
    k_gemm<true><<<dim3(NB / 128, (D + 127) / 128), 256, 0, stream>>>(pg, pW1, pb1, pt, NB, D, D);
    k_gemm<false><<<dim3(NB / 128, (D + 127) / 128), 256, 0, stream>>>(pt, pW2, pb2, pg, NB, D, D);
    k_norm<<<NB, 64, 0, stream>>>(pg, featH, featL, v * NB);
  }

  k_logits_mfma<<<dim3(4096 / 128, 4096 / 64), 256, 0, stream>>>(featH, featL, (float*)d_out);
  hipMemsetAsync((float*)d_out + (size_t)4096 * 4095, 0, (size_t)4096 * 4, stream);
}

// Round 5
// 10496.592 us; speedup vs baseline: 2.2505x; 1.2223x over previous
//
#include <hip/hip_runtime.h>

#define NN 81920
#define NE 180224
#define NB 2048
#define D 300
#define NL 5
#define CH 8192
#define KP1 320          // padded K for GEMM1 (agg planes stride)
#define NP1 640          // padded N for GEMM1 (slab stride)
#define KP2 640          // padded K for GEMM2 (= NP1)
#define NP2 384          // padded N for GEMM2 (128-multiple for 128x128 tiles)
#define FKP 320          // feature planes stride (logits K)

static constexpr float TEMP_INV = 25.0f;   // 1/0.04
static constexpr float BN_EPS_C = 1e-5f;

typedef __attribute__((ext_vector_type(8))) short short8;
typedef __attribute__((ext_vector_type(4))) float f32x4;

__device__ inline void split_bf16(float v, short& hi, short& lo) {
  unsigned u = __float_as_uint(v);
  hi = (short)(u >> 16);
  float r = v - __uint_as_float(u & 0xffff0000u);
  lo = (short)(__float_as_uint(r) >> 16);
}

// ---------------- init h = atom_emb1[x0] + atom_emb2[x1] ----------------
__global__ void k_init_h(const int* __restrict__ x, const float* __restrict__ ae1,
                         const float* __restrict__ ae2, float* __restrict__ h) {
  int i = blockIdx.x;
  int i0 = x[2 * i], i1 = x[2 * i + 1];
  const float* r1 = ae1 + (size_t)i0 * D;
  const float* r2 = ae2 + (size_t)i1 * D;
  float* ho = h + (size_t)i * D;
  for (int f = threadIdx.x; f < D; f += blockDim.x) ho[f] = r1[f] + r2[f];
}

// ---------------- CSR build ----------------
__global__ void k_count(const int* __restrict__ ei, int* __restrict__ cnt) {
  int e = blockIdx.x * blockDim.x + threadIdx.x;
  if (e < NE) atomicAdd(&cnt[ei[NE + e]], 1);
}

__global__ void k_scan(const int* __restrict__ cnt, int* __restrict__ rs) {
  __shared__ int sdata[1024];
  int t = threadIdx.x;
  int base = t * 80;                 // 1024*80 == 81920
  int s = 0;
  for (int j = 0; j < 80; ++j) s += cnt[base + j];
  sdata[t] = s;
  __syncthreads();
  for (int off = 1; off < 1024; off <<= 1) {
    int v = (t >= off) ? sdata[t - off] : 0;
    __syncthreads();
    sdata[t] += v;
    __syncthreads();
  }
  int run = sdata[t] - s;
  for (int j = 0; j < 80; ++j) { rs[base + j] = run; run += cnt[base + j]; }
  if (t == 1023) rs[NN] = run;
}

__global__ void k_bucket(const int* __restrict__ ei, const int* __restrict__ ea,
                         const int* __restrict__ rs, int* __restrict__ fill,
                         int* __restrict__ srcs, int* __restrict__ attrs) {
  int e = blockIdx.x * blockDim.x + threadIdx.x;
  if (e >= NE) return;
  int d = ei[NE + e];
  int p = rs[d] + atomicAdd(&fill[d], 1);
  srcs[p] = ei[e];
  attrs[p] = ea[2 * e] | (ea[2 * e + 1] << 8);
}

// ---------------- gather (+ fused BN-apply+ReLU of previous layer) ----------------
// BN=false (layer 0): u(x) = x            BN=true: u(x) = relu(x*sc + sh)
template <bool BN>
__global__ void k_gather(const float* __restrict__ h, const int* __restrict__ rs,
                         const int* __restrict__ srcs, const int* __restrict__ attrs,
                         const float* __restrict__ T1, const float* __restrict__ T2,
                         const float* __restrict__ scsh,
                         short* __restrict__ aggH, short* __restrict__ aggL) {
  int i = blockIdx.x;
  int j0 = rs[i], j1 = rs[i + 1];
  int t = threadIdx.x;               // 128
  int f0 = t, f1 = t + 128, f2 = t + 256;
  float sc0 = 0, sh0 = 0, sc1 = 0, sh1 = 0, sc2 = 0, sh2 = 0;
  if (BN) {
    sc0 = scsh[f0]; sh0 = scsh[D + f0];
    sc1 = scsh[f1]; sh1 = scsh[D + f1];
    if (f2 < D) { sc2 = scsh[f2]; sh2 = scsh[D + f2]; }
  }
  auto u0 = [&](float x) { return BN ? fmaxf(fmaf(x, sc0, sh0), 0.f) : x; };
  auto u1 = [&](float x) { return BN ? fmaxf(fmaf(x, sc1, sh1), 0.f) : x; };
  auto u2 = [&](float x) { return BN ? fmaxf(fmaf(x, sc2, sh2), 0.f) : x; };
  const float* hi = h + (size_t)i * D;
  float a0 = u0(hi[f0]) + T1[4 * D + f0] + T2[f0];
  float a1 = u1(hi[f1]) + T1[4 * D + f1] + T2[f1];
  float a2 = (f2 < D) ? (u2(hi[f2]) + T1[4 * D + f2] + T2[f2]) : 0.f;
  for (int j = j0; j < j1; ++j) {
    int s = srcs[j];
    int at = attrs[j];
    const float* hs = h + (size_t)s * D;
    const float* t1 = T1 + (size_t)(at & 255) * D;
    const float* t2 = T2 + (size_t)(at >> 8) * D;
    a0 += u0(hs[f0]) + t1[f0] + t2[f0];
    a1 += u1(hs[f1]) + t1[f1] + t2[f1];
    if (f2 < D) a2 += u2(hs[f2]) + t1[f2] + t2[f2];
  }
  size_t base = (size_t)i * KP1;
  short hh, ll;
  split_bf16(a0, hh, ll); aggH[base + f0] = hh; aggL[base + f0] = ll;
  split_bf16(a1, hh, ll); aggH[base + f1] = hh; aggL[base + f1] = ll;
  if (f2 < KP1) {
    split_bf16(a2, hh, ll); aggH[base + f2] = hh; aggL[base + f2] = ll;
  }
}

// ---------------- weight pre-transpose + split:  T[n][k] = W[k][n], zero-padded --------
__global__ void k_prepw(const float* __restrict__ W, short* __restrict__ TH,
                        short* __restrict__ TL, int K, int Nc, int Kp, int Np) {
  int idx = blockIdx.x * blockDim.x + threadIdx.x;
  int per = Np * Kp;
  if (idx >= NL * per) return;
  int l = idx / per, r = idx % per;
  int n = r / Kp, k = r % Kp;
  float v = (n < Nc && k < K) ? W[(size_t)l * K * Nc + (size_t)k * Nc + n] : 0.f;
  short hi, lo;
  split_bf16(v, hi, lo);
  TH[idx] = hi;
  TL[idx] = lo;
}

// ---------------- split-bf16 MFMA GEMM, tile 128x128, 4 waves (64x64/wave), no LDS ----
// MODE 0: relu(bias+C) -> split planes (GEMM1)
// MODE 1: bias+C -> fp32 Cf (col<maskN) + fused BN-stats atomics (GEMM2)
template <int MODE, int KK>
__global__ __launch_bounds__(256) void k_mfma_gemm(
    const short* __restrict__ AH, const short* __restrict__ AL,
    const short* __restrict__ BH, const short* __restrict__ BL,
    const float* __restrict__ bias, int biasN,
    short* __restrict__ CHp, short* __restrict__ CLp, int ldcp,
    float* __restrict__ Cf, int ldcf, int maskN, float* __restrict__ stats) {
  int lane = threadIdx.x & 63;
  int w = threadIdx.x >> 6;
  int m0 = blockIdx.x * 128 + (w >> 1) * 64;
  int n0 = blockIdx.y * 128 + (w & 1) * 64;
  int rl = lane & 15;
  int kg = (lane >> 4) * 8;
  f32x4 acc[4][4] = {};
  for (int k0 = 0; k0 < KK; k0 += 32) {
    int kk = k0 + kg;
    short8 aH[4], aL[4], bH[4], bL[4];
#pragma unroll
    for (int rf = 0; rf < 4; ++rf) {
      size_t off = (size_t)(m0 + rf * 16 + rl) * KK + kk;
      aH[rf] = *(const short8*)(AH + off);
      aL[rf] = *(const short8*)(AL + off);
    }
#pragma unroll
    for (int cf = 0; cf < 4; ++cf) {
      size_t off = (size_t)(n0 + cf * 16 + rl) * KK + kk;
      bH[cf] = *(const short8*)(BH + off);
      bL[cf] = *(const short8*)(BL + off);
    }
#pragma unroll
    for (int rf = 0; rf < 4; ++rf)
#pragma unroll
      for (int cf = 0; cf < 4; ++cf) {
        acc[rf][cf] = __builtin_amdgcn_mfma_f32_16x16x32_bf16(aH[rf], bH[cf], acc[rf][cf], 0, 0, 0);
        acc[rf][cf] = __builtin_amdgcn_mfma_f32_16x16x32_bf16(aH[rf], bL[cf], acc[rf][cf], 0, 0, 0);
        acc[rf][cf] = __builtin_amdgcn_mfma_f32_16x16x32_bf16(aL[rf], bH[cf], acc[rf][cf], 0, 0, 0);
      }
  }
#pragma unroll
  for (int cf = 0; cf < 4; ++cf) {
    int col = n0 + cf * 16 + rl;
    float bv = (col < biasN) ? bias[col] : 0.f;
    float s = 0.f, q = 0.f;
#pragma unroll
    for (int rf = 0; rf < 4; ++rf) {
#pragma unroll
      for (int i = 0; i < 4; ++i) {
        int row = m0 + rf * 16 + (lane >> 4) * 4 + i;
        float v = acc[rf][cf][i] + bv;
        if (MODE == 0) {
          v = fmaxf(v, 0.f);
          short hi, lo;
          split_bf16(v, hi, lo);
          CHp[(size_t)row * ldcp + col] = hi;
          CLp[(size_t)row * ldcp + col] = lo;
        } else {
          if (col < maskN) Cf[(size_t)row * ldcf + col] = v;
          s += v; q += v * v;
        }
      }
    }
    if (MODE == 1) {
      s += __shfl_xor(s, 16); s += __shfl_xor(s, 32);
      q += __shfl_xor(q, 16); q += __shfl_xor(q, 32);
      if ((lane >> 4) == 0 && col < maskN) {
        atomicAdd(&stats[col], s);
        atomicAdd(&stats[D + col], q);
      }
    }
  }
}

// ---------------- fp32 tiled GEMM (projector only) ----------------
template <bool RELU>
__global__ __launch_bounds__(256) void k_gemm(const float* __restrict__ A,
                                              const float* __restrict__ Bm,
                                              const float* __restrict__ bias,
                                              float* __restrict__ C,
                                              int M, int K, int Nc) {
  __shared__ float As[8][132];
  __shared__ float Bs[8][132];
  int tid = threadIdx.x;
  int tx = tid & 15, ty = tid >> 4;
  int m0 = blockIdx.x * 128, n0 = blockIdx.y * 128;
  float acc[8][8] = {};
  int ar = tid >> 1, akq = (tid & 1) * 4;
  int bk = tid >> 5, bn = (tid & 31) * 4;
  for (int kk = 0; kk < K; kk += 8) {
    {
      int gr = m0 + ar, gk = kk + akq;
      if (gr < M && gk + 3 < K) {
        float4 v = *(const float4*)(A + (size_t)gr * K + gk);
        As[akq + 0][ar] = v.x; As[akq + 1][ar] = v.y;
        As[akq + 2][ar] = v.z; As[akq + 3][ar] = v.w;
      } else {
#pragma unroll
        for (int u = 0; u < 4; ++u)
          As[akq + u][ar] = (gr < M && gk + u < K) ? A[(size_t)gr * K + gk + u] : 0.f;
      }
    }
    {
      int gk = kk + bk, gn = n0 + bn;
      if (gk < K && gn + 3 < Nc) {
        *(float4*)&Bs[bk][bn] = *(const float4*)(Bm + (size_t)gk * Nc + gn);
      } else {
#pragma unroll
        for (int u = 0; u < 4; ++u)
          Bs[bk][bn + u] = (gk < K && gn + u < Nc) ? Bm[(size_t)gk * Nc + gn + u] : 0.f;
      }
    }
    __syncthreads();
#pragma unroll
    for (int k = 0; k < 8; ++k) {
      float4 a0 = *(const float4*)&As[k][ty * 8];
      float4 a1 = *(const float4*)&As[k][ty * 8 + 4];
      float4 b0 = *(const float4*)&Bs[k][tx * 8];
      float4 b1 = *(const float4*)&Bs[k][tx * 8 + 4];
      float av[8] = {a0.x, a0.y, a0.z, a0.w, a1.x, a1.y, a1.z, a1.w};
      float bv[8] = {b0.x, b0.y, b0.z, b0.w, b1.x, b1.y, b1.z, b1.w};
#pragma unroll
      for (int i = 0; i < 8; ++i)
#pragma unroll
        for (int j = 0; j < 8; ++j) acc[i][j] = fmaf(av[i], bv[j], acc[i][j]);
    }
    __syncthreads();
  }
  int rbase = m0 + ty * 8, cbase = n0 + tx * 8;
#pragma unroll
  for (int i = 0; i < 8; ++i) {
    int r = rbase + i;
    if (r >= M) break;
#pragma unroll
    for (int j = 0; j < 8; ++j) {
      int c = cbase + j;
      if (c >= Nc) continue;
      float v = acc[i][j] + bias[c];
      if (RELU) v = fmaxf(v, 0.f);
      C[(size_t)r * Nc + c] = v;
    }
  }
}

// ---------------- BN finalize (stats -> scale/shift) ----------------
__global__ void k_bnfinal(const float* __restrict__ stats, const float* __restrict__ g,
                          const float* __restrict__ b, float* __restrict__ scsh) {
  int t = threadIdx.x;
  if (t >= D) return;
  float mean = stats[t] * (1.0f / NN);
  float var = stats[D + t] * (1.0f / NN) - mean * mean;
  float inv = rsqrtf(var + BN_EPS_C);
  float sc = g[t] * inv;
  scsh[t] = sc;
  scsh[D + t] = b[t] - mean * sc;
}

// ---------------- pooling (batch sorted) + fused last-layer BN (affine, no relu) ------
__global__ void k_gstart(const int* __restrict__ batch, int* __restrict__ gs) {
  int i = blockIdx.x * blockDim.x + threadIdx.x;
  if (i >= NN) return;
  int b = batch[i];
  int bp = (i == 0) ? -1 : batch[i - 1];
  for (int q = bp + 1; q <= b; ++q) gs[q] = i;
  if (i == NN - 1)
    for (int q = b + 1; q <= NB; ++q) gs[q] = NN;
}

__global__ void k_poolseg(const float* __restrict__ h, const int* __restrict__ gs,
                          const float* __restrict__ scsh, float* __restrict__ g) {
  int b = blockIdx.x;
  int j0 = gs[b], j1 = gs[b + 1];
  int t = threadIdx.x;               // 128
  float s0 = 0, s1 = 0, s2 = 0;
  int c2 = t + 256;
  for (int j = j0; j < j1; ++j) {
    const float* row = h + (size_t)j * D;
    s0 += row[t];
    s1 += row[t + 128];
    if (c2 < D) s2 += row[c2];
  }
  bool nz = j1 > j0;
  float invc = nz ? 1.f / (float)(j1 - j0) : 0.f;
  float* go = g + (size_t)b * D;
  go[t] = nz ? fmaf(s0 * invc, scsh[t], scsh[D + t]) : 0.f;
  go[t + 128] = nz ? fmaf(s1 * invc, scsh[t + 128], scsh[D + t + 128]) : 0.f;
  if (c2 < D) go[c2] = nz ? fmaf(s2 * invc, scsh[c2], scsh[D + c2]) : 0.f;
}

// ---------------- L2 normalize -> split feature planes [4096, FKP] ----------------
__global__ void k_norm(const float* __restrict__ pin, short* __restrict__ FH,
                       short* __restrict__ FL, int ro) {
  int b = blockIdx.x;
  int t = threadIdx.x;               // 64
  const float* row = pin + (size_t)b * D;
  float q = 0;
  for (int c = t; c < D; c += 64) { float v = row[c]; q += v * v; }
#pragma unroll
  for (int off = 32; off > 0; off >>= 1) q += __shfl_down(q, off);
  q = __shfl(q, 0);
  float inv = 1.f / fmaxf(sqrtf(q), 1e-12f);
  size_t base = (size_t)(ro + b) * FKP;
  for (int c = t; c < FKP; c += 64) {
    float v = (c < D) ? row[c] * inv : 0.f;
    short hi, lo;
    split_bf16(v, hi, lo);
    FH[base + c] = hi;
    FL[base + c] = lo;
  }
}

// ---------------- MFMA sim = F F^T fused with NT-Xent logits layout ----------------
__global__ __launch_bounds__(256) void k_logits_mfma(const short* __restrict__ FH,
                                                     const short* __restrict__ FL,
                                                     float* __restrict__ out) {
  int lane = threadIdx.x & 63;
  int w = threadIdx.x >> 6;
  int m0 = blockIdx.x * 128 + (w >> 1) * 64;
  int n0 = blockIdx.y * 128 + (w & 1) * 64;
  int rl = lane & 15;
  int kg = (lane >> 4) * 8;
  f32x4 acc[4][4] = {};
  for (int k0 = 0; k0 < FKP; k0 += 32) {
    int kk = k0 + kg;
    short8 aH[4], aL[4], bH[4], bL[4];
#pragma unroll
    for (int rf = 0; rf < 4; ++rf) {
      size_t off = (size_t)(m0 + rf * 16 + rl) * FKP + kk;
      aH[rf] = *(const short8*)(FH + off);
      aL[rf] = *(const short8*)(FL + off);
    }
#pragma unroll
    for (int cf = 0; cf < 4; ++cf) {
      size_t off = (size_t)(n0 + cf * 16 + rl) * FKP + kk;
      bH[cf] = *(const short8*)(FH + off);
      bL[cf] = *(const short8*)(FL + off);
    }
#pragma unroll
    for (int rf = 0; rf < 4; ++rf)
#pragma unroll
      for (int cf = 0; cf < 4; ++cf) {
        acc[rf][cf] = __builtin_amdgcn_mfma_f32_16x16x32_bf16(aH[rf], bH[cf], acc[rf][cf], 0, 0, 0);
        acc[rf][cf] = __builtin_amdgcn_mfma_f32_16x16x32_bf16(aH[rf], bL[cf], acc[rf][cf], 0, 0, 0);
        acc[rf][cf] = __builtin_amdgcn_mfma_f32_16x16x32_bf16(aL[rf], bH[cf], acc[rf][cf], 0, 0, 0);
      }
  }
#pragma unroll
  for (int rf = 0; rf < 4; ++rf) {
#pragma unroll
    for (int cf = 0; cf < 4; ++cf) {
      int c = n0 + cf * 16 + rl;
#pragma unroll
      for (int i = 0; i < 4; ++i) {
        int r = m0 + rf * 16 + (lane >> 4) * 4 + i;
        if (c == r) continue;
        float v = acc[rf][cf][i] * TEMP_INV;
        int posj = (r + NB) & 4095;
        int slot = (c == posj) ? 0 : (1 + c - (c > r) - (c > posj));
        out[(size_t)r * 4095 + slot] = v;
      }
    }
  }
}

// ---------------- host ----------------
extern "C" void kernel_launch(void* const* d_in, const int* in_sizes, int n_in,
                              void* d_out, int out_size, void* d_ws, size_t ws_size,
                              hipStream_t stream) {
  const int* xs[2] = {(const int*)d_in[0], (const int*)d_in[4]};
  const int* eis[2] = {(const int*)d_in[1], (const int*)d_in[5]};
  const int* eas[2] = {(const int*)d_in[2], (const int*)d_in[6]};
  const int* bts[2] = {(const int*)d_in[3], (const int*)d_in[7]};
  const float* ae1 = (const float*)d_in[8];
  const float* ae2 = (const float*)d_in[9];
  const float* ee1 = (const float*)d_in[10];
  const float* ee2 = (const float*)d_in[11];
  const float* W1 = (const float*)d_in[12];
  const float* b1 = (const float*)d_in[13];
  const float* W2 = (const float*)d_in[14];
  const float* b2 = (const float*)d_in[15];
  const float* bng = (const float*)d_in[16];
  const float* bnb = (const float*)d_in[17];
  const float* pW1 = (const float*)d_in[18];
  const float* pb1 = (const float*)d_in[19];
  const float* pW2 = (const float*)d_in[20];
  const float* pb2 = (const float*)d_in[21];

  char* p = (char*)d_ws;
  auto alloc = [&](size_t bytes) -> void* {
    void* q = (void*)p;
    p += (bytes + 255) & ~(size_t)255;
    return q;
  };
  float* h    = (float*)alloc((size_t)NN * D * 4);
  short* aggH = (short*)alloc((size_t)NN * KP1 * 2);
  short* aggL = (short*)alloc((size_t)NN * KP1 * 2);
  short* slabH = (short*)alloc((size_t)CH * NP1 * 2);
  short* slabL = (short*)alloc((size_t)CH * NP1 * 2);
  short* w1tH = (short*)alloc((size_t)NL * NP1 * KP1 * 2);
  short* w1tL = (short*)alloc((size_t)NL * NP1 * KP1 * 2);
  short* w2tH = (short*)alloc((size_t)NL * NP2 * KP2 * 2);
  short* w2tL = (short*)alloc((size_t)NL * NP2 * KP2 * 2);
  short* featH = (short*)alloc((size_t)2 * NB * FKP * 2);
  short* featL = (short*)alloc((size_t)2 * NB * FKP * 2);
  int* cnt    = (int*)alloc((size_t)NN * 4);
  int* rs     = (int*)alloc((size_t)(NN + 1) * 4);
  int* srcs   = (int*)alloc((size_t)NE * 4);
  int* attrs  = (int*)alloc((size_t)NE * 4);
  float* stats = (float*)alloc(600 * 4);
  float* scsh  = (float*)alloc(600 * 4);
  int* gstart  = (int*)alloc((size_t)(NB + 1) * 4);
  float* pg   = (float*)alloc((size_t)NB * D * 4);
  float* pt   = (float*)alloc((size_t)NB * D * 4);
  // total ~ 240 MB

  k_prepw<<<(NL * NP1 * KP1 + 255) / 256, 256, 0, stream>>>(W1, w1tH, w1tL, 300, 600, KP1, NP1);
  k_prepw<<<(NL * NP2 * KP2 + 255) / 256, 256, 0, stream>>>(W2, w2tH, w2tL, 600, 300, KP2, NP2);

  for (int v = 0; v < 2; ++v) {
    k_init_h<<<NN, 128, 0, stream>>>(xs[v], ae1, ae2, h);
    hipMemsetAsync(cnt, 0, (size_t)NN * 4, stream);
    k_count<<<(NE + 255) / 256, 256, 0, stream>>>(eis[v], cnt);
    k_scan<<<1, 1024, 0, stream>>>(cnt, rs);
    hipMemsetAsync(cnt, 0, (size_t)NN * 4, stream);
    k_bucket<<<(NE + 255) / 256, 256, 0, stream>>>(eis[v], eas[v], rs, cnt, srcs, attrs);

    for (int l = 0; l < NL; ++l) {
      if (l == 0)
        k_gather<false><<<NN, 128, 0, stream>>>(h, rs, srcs, attrs, ee1 + (size_t)l * 6 * D,
                                                ee2 + (size_t)l * 3 * D, nullptr, aggH, aggL);
      else
        k_gather<true><<<NN, 128, 0, stream>>>(h, rs, srcs, attrs, ee1 + (size_t)l * 6 * D,
                                               ee2 + (size_t)l * 3 * D, scsh, aggH, aggL);
      hipMemsetAsync(stats, 0, 600 * 4, stream);
      for (int c0 = 0; c0 < NN; c0 += CH) {
        k_mfma_gemm<0, KP1><<<dim3(CH / 128, NP1 / 128), 256, 0, stream>>>(
            aggH + (size_t)c0 * KP1, aggL + (size_t)c0 * KP1,
            w1tH + (size_t)l * NP1 * KP1, w1tL + (size_t)l * NP1 * KP1,
            b1 + (size_t)l * 600, 600, slabH, slabL, NP1, nullptr, 0, 0, nullptr);
        k_mfma_gemm<1, KP2><<<dim3(CH / 128, NP2 / 128), 256, 0, stream>>>(
            slabH, slabL,
            w2tH + (size_t)l * NP2 * KP2, w2tL + (size_t)l * NP2 * KP2,
            b2 + (size_t)l * 300, 300, nullptr, nullptr, 0,
            h + (size_t)c0 * D, D, 300, stats);
      }
      k_bnfinal<<<1, 320, 0, stream>>>(stats, bng + (size_t)l * D, bnb + (size_t)l * D, scsh);
    }

    k_gstart<<<(NN + 255) / 256, 256, 0, stream>>>(bts[v], gstart);
    k_poolseg<<<NB, 128, 0, stream>>>(h, gstart, scsh, pg);
    k_gemm<true><<<dim3(NB / 128, (D + 127) / 128), 256, 0, stream>>>(pg, pW1, pb1, pt, NB, D, D);
    k_gemm<false><<<dim3(NB / 128, (D + 127) / 128), 256, 0, stream>>>(pt, pW2, pb2, pg, NB, D, D);
    k_norm<<<NB, 64, 0, stream>>>(pg, featH, featL, v * NB);
  }

  k_logits_mfma<<<dim3(4096 / 128, 4096 / 128), 256, 0, stream>>>(featH, featL, (float*)d_out);
  hipMemsetAsync((float*)d_out + (size_t)4096 * 4095, 0, (size_t)4096 * 4, stream);
}